// Round 9
// baseline (295.506 us; speedup 1.0000x reference)
//
#include <hip/hip_runtime.h>
#include <hip/hip_bf16.h>
#include <float.h>
#include <math.h>

#define N_NODES 20000
#define N_EDGES 320000
#define ET      (N_EDGES + N_NODES)   // edges + self loops
#define ETB     ((ET + 255) / 256)     // fill blocks
#define NPB     ((N_NODES + 255) / 256)// perm blocks
#define DCH     512
#define D2      1024                   // fused l|r width
#define INCH    55
#define INCHP   64
#define OUTCH   49
#define OUTCHP  128
#define NB      130                    // degree buckets (clamped)

typedef _Float16 f16;
typedef _Float16 f16x2 __attribute__((ext_vector_type(2)));
typedef _Float16 f16x8 __attribute__((ext_vector_type(8)));
typedef float    f32x4 __attribute__((ext_vector_type(4)));

#define GPTR(p) ((const __attribute__((address_space(1))) void*)(p))
#define LPTR(p) ((__attribute__((address_space(3))) void*)(p))

// ---------------- fused prep: zeroing + conv_x + 5 weight transposes ----------
__device__ __forceinline__ void transpose_tile(const float* __restrict__ w, f16* __restrict__ o,
                                               int K, int N, int Kp, int bx, int by, int t,
                                               f16 (*tile)[66]) {
    int k0 = by * 64, n0 = bx * 64;
    #pragma unroll
    for (int r = 0; r < 16; ++r) {
        int kl = (t >> 6) + r * 4, nl = t & 63;
        int gk = k0 + kl, gn = n0 + nl;
        tile[kl][nl] = (gk < K && gn < N) ? (f16)w[(size_t)gk * N + gn] : (f16)0.f;
    }
    __syncthreads();
    #pragma unroll
    for (int r = 0; r < 16; ++r) {
        int kl = t & 63, nl = (t >> 6) + r * 4;
        o[(size_t)(n0 + nl) * Kp + k0 + kl] = tile[kl][nl];
    }
}

__global__ __launch_bounds__(256) void prep_all(const float* __restrict__ x, f16* __restrict__ x_h,
                                                const float* __restrict__ w1l, const float* __restrict__ w1r,
                                                const float* __restrict__ w2l, const float* __restrict__ w2r,
                                                const float* __restrict__ wc,
                                                f16* __restrict__ w1T, f16* __restrict__ w2T,
                                                f16* __restrict__ wcT,
                                                int* __restrict__ zeroA,   // counts+cursor contiguous (40000)
                                                int* __restrict__ bcur) {
    __shared__ f16 tile[64][66];
    int b = blockIdx.x, t = threadIdx.x;
    if (b < 157) {
        int i = b * 256 + t;
        if (i < 40000) zeroA[i] = 0;
        else if (i < 40000 + NB) bcur[i - 40000] = 0;
        return;
    }
    b -= 157;
    if (b < 5000) {
        int i = b * 256 + t;
        int r = i >> 6, c = i & 63;
        x_h[i] = (c < INCH) ? (f16)x[r * INCH + c] : (f16)0.f;
        return;
    }
    b -= 5000;
    if (b < 8)  { transpose_tile(w1l, w1T, INCH, DCH, INCHP, b, 0, t, tile); return; }
    b -= 8;
    if (b < 8)  { transpose_tile(w1r, w1T + (size_t)DCH * INCHP, INCH, DCH, INCHP, b, 0, t, tile); return; }
    b -= 8;
    if (b < 64) { transpose_tile(w2l, w2T, DCH, DCH, DCH, b & 7, b >> 3, t, tile); return; }
    b -= 64;
    if (b < 64) { transpose_tile(w2r, w2T + (size_t)DCH * DCH, DCH, DCH, DCH, b & 7, b >> 3, t, tile); return; }
    b -= 64;
    transpose_tile(wc, wcT, DCH, OUTCH, DCH, b & 1, b >> 1, t, tile);
}

// ---------------- CSR build (by dst) ----------------
__global__ void count_kernel(const int* __restrict__ ei, int* __restrict__ counts) {
    int e = blockIdx.x * blockDim.x + threadIdx.x;
    if (e >= ET) return;
    int d = (e < N_EDGES) ? ei[N_EDGES + e] : (e - N_EDGES);
    atomicAdd(&counts[d], 1);
}

// node prefix-sum + degree-bucket histogram + DESCENDING bucket prefix (LPT)
__global__ void scan_kernel(const int* __restrict__ counts, int* __restrict__ row_ptr,
                            int* __restrict__ bbase) {
    __shared__ int sdata[1024];
    __shared__ int bh[NB];
    int t = threadIdx.x;
    if (t < NB) bh[t] = 0;
    __syncthreads();
    int per = (N_NODES + 1023) / 1024;
    int b = t * per, e = min(N_NODES, b + per);
    int sum = 0;
    for (int i = b; i < e; ++i) {
        int c = counts[i];
        sum += c;
        atomicAdd(&bh[min(c, NB - 1)], 1);
    }
    sdata[t] = sum;
    __syncthreads();
    for (int off = 1; off < 1024; off <<= 1) {
        int v = (t >= off) ? sdata[t - off] : 0;
        __syncthreads();
        sdata[t] += v;
        __syncthreads();
    }
    int run = (t == 0) ? 0 : sdata[t - 1];
    if (t == 0) row_ptr[0] = 0;
    for (int i = b; i < e; ++i) { run += counts[i]; row_ptr[i + 1] = run; }
    __syncthreads();
    if (t == 0) {
        int acc = 0;
        for (int j = NB - 1; j >= 0; --j) { bbase[j] = acc; acc += bh[j]; }  // LPT
    }
}

// fill CSR + degree-bucket scatter (hierarchical atomics). Intra-bucket order
// schedule-dependent; per-node outputs independent -> d_out deterministic.
__global__ __launch_bounds__(256) void fill_perm_kernel(const int* __restrict__ ei,
                                                        const int* __restrict__ row_ptr,
                                                        const int* __restrict__ counts,
                                                        const int* __restrict__ bbase,
                                                        int* __restrict__ cursor,
                                                        int* __restrict__ bcur,
                                                        int* __restrict__ esrc,
                                                        int* __restrict__ perm) {
    int blk = blockIdx.x;
    if (blk < ETB) {                        // CSR fill segment
        int e = blk * 256 + threadIdx.x;
        if (e >= ET) return;
        int s, d;
        if (e < N_EDGES) { s = ei[e]; d = ei[N_EDGES + e]; }
        else             { s = d = e - N_EDGES; }
        int pos = row_ptr[d] + atomicAdd(&cursor[d], 1);
        esrc[pos] = s;
        return;
    }
    blk -= ETB;
    __shared__ int hist[NB], basep[NB];
    int t = threadIdx.x;
    for (int i = t; i < NB; i += 256) hist[i] = 0;
    __syncthreads();
    int n = blk * 256 + t;
    bool valid = n < N_NODES;
    int bkt = 0, rl = 0;
    if (valid) {
        bkt = min(counts[n], NB - 1);
        rl = atomicAdd(&hist[bkt], 1);
    }
    __syncthreads();
    for (int i = t; i < NB; i += 256)
        if (hist[i] > 0) basep[i] = atomicAdd(&bcur[i], hist[i]);
    __syncthreads();
    if (valid) perm[bbase[bkt] + basep[bkt] + rl] = n;
}

// ---------------- fp16 MFMA GEMM (R7 structure: BK=64, T2 XOR swizzle, T1) ------
// RATIONALE (R8 post-mortem): BK=32 dbuf doubled barrier count and regressed
// (54 µs, m99/m100 lesson reproduced). BK=64 single-buffer, 2 barriers/step.
template<int OUT_F16, int DUAL>
__global__ __launch_bounds__(256) void gemm_f16(const f16* __restrict__ A,
                                                const f16* __restrict__ BT,
                                                const float* __restrict__ bl,
                                                const float* __restrict__ br,
                                                void* __restrict__ Cout,
                                                int M, int Ka, int Nv, int ldc) {
    __shared__ __align__(16) f16 As[128][64];
    __shared__ __align__(16) f16 Bs[128][64];
    const int tid = threadIdx.x;
    const int w = tid >> 6, lane = tid & 63;
    int nbx = gridDim.x;
    int nwg = nbx * gridDim.y;
    int bid = blockIdx.y * nbx + blockIdx.x;
    if ((nwg & 7) == 0) bid = (bid & 7) * (nwg >> 3) + (bid >> 3);   // XCD swizzle (T1)
    const int m0 = (bid / nbx) * 128, n0 = (bid % nbx) * 128;
    const int wr = (w >> 1) * 64, wc = (w & 1) * 64;
    const int lrow = lane & 15, lk = lane >> 4;
    const int sw = lrow & 7;

    f32x4 acc[4][4] = {};

    for (int k0 = 0; k0 < Ka; k0 += 64) {
        #pragma unroll
        for (int i = 0; i < 4; ++i) {
            int idx = tid + 256 * i;
            int row = idx >> 3;
            int cg  = (idx & 7) ^ (row & 7);
            int gm = m0 + row; gm = gm < M ? gm : M - 1;
            const f16* gp = A + (size_t)gm * Ka + k0 + cg * 8;
            f16* lp = &As[0][0] + (size_t)(w * 64 + 256 * i) * 8;
            __builtin_amdgcn_global_load_lds(GPTR(gp), LPTR(lp), 16, 0, 0);
        }
        #pragma unroll
        for (int i = 0; i < 4; ++i) {
            int idx = tid + 256 * i;
            int row = idx >> 3;
            int cg  = (idx & 7) ^ (row & 7);
            const f16* gp = BT + (size_t)(n0 + row) * Ka + k0 + cg * 8;
            f16* lp = &Bs[0][0] + (size_t)(w * 64 + 256 * i) * 8;
            __builtin_amdgcn_global_load_lds(GPTR(gp), LPTR(lp), 16, 0, 0);
        }
        __syncthreads();
        #pragma unroll
        for (int kk = 0; kk < 64; kk += 32) {
            f16x8 af[4], bf[4];
            #pragma unroll
            for (int m = 0; m < 4; ++m)
                af[m] = *(const f16x8*)&As[wr + m * 16 + lrow][(((kk >> 3) + lk) ^ sw) * 8];
            #pragma unroll
            for (int n = 0; n < 4; ++n)
                bf[n] = *(const f16x8*)&Bs[wc + n * 16 + lrow][(((kk >> 3) + lk) ^ sw) * 8];
            #pragma unroll
            for (int m = 0; m < 4; ++m)
                #pragma unroll
                for (int n = 0; n < 4; ++n)
                    acc[m][n] = __builtin_amdgcn_mfma_f32_16x16x32_f16(af[m], bf[n], acc[m][n], 0, 0, 0);
        }
        __syncthreads();
    }

    const int orow = (lane >> 4) * 4, ocol = lane & 15;   // C/D map (m89)
    #pragma unroll
    for (int m = 0; m < 4; ++m) {
        #pragma unroll
        for (int r = 0; r < 4; ++r) {
            int gm = m0 + wr + m * 16 + orow + r;
            if (gm >= M) continue;
            #pragma unroll
            for (int n = 0; n < 4; ++n) {
                int gn = n0 + wc + n * 16 + ocol;
                if (gn >= Nv) continue;
                float bv = DUAL ? (gn < DCH ? bl[gn] : br[gn - DCH]) : bl[gn];
                float v = acc[m][n][r] + bv;
                if (OUT_F16) ((f16*)Cout)[(size_t)gm * ldc + gn] = (f16)v;
                else         ((float*)Cout)[(size_t)gm * ldc + gn] = v;
            }
        }
    }
}

// ---------------- fused GATv2 edge phase v8: FOUR nodes per wave ----------------
// 4 independent online-softmax chains per wave: each chain's shfl-reduce/exp/
// gather latency hides under the other 3 chains' VALU. Ping-pong unroll-2,
// defer-max THR=8. launch_bounds(256,4) caps VGPR at 128.
#define LOAD1(DST, i, pp)                                                       \
  { int q_ = (pp) < dcap ? (pp) : dcap - 1;                                     \
    int s_ = __shfl(pre##i, q_, 64);                                            \
    DST##i.v = *(const f16x8*)(xlr + (size_t)s_ * D2 + lane * 8); }

#define PROC1(SRC, i, pp)                                                       \
  { float sc = 0.f;                                                             \
    _Pragma("unroll")                                                           \
    for (int j = 0; j < 4; ++j) {                                               \
        f16x2 u = SRC##i.q[j] + xr##i.q[j];                                     \
        f16x2 l = __builtin_elementwise_max(u, u * k02);                        \
        sc = __builtin_amdgcn_fdot2(l, at2[j], sc, false);                      \
    }                                                                           \
    sc += __shfl_xor(sc, 8, 64); sc += __shfl_xor(sc, 4, 64);                   \
    sc += __shfl_xor(sc, 2, 64); sc += __shfl_xor(sc, 1, 64);                   \
    if ((pp) >= deg##i) sc = -INFINITY;                                         \
    if (__any(sc > m##i + 8.f)) {                                               \
        float mn = fmaxf(m##i, sc); float f_ = __expf(m##i - mn);               \
        d##i *= f_;                                                             \
        _Pragma("unroll") for (int j = 0; j < 8; ++j) acc##i[j] *= f_;          \
        m##i = mn;                                                              \
    }                                                                           \
    float w_ = __expf(sc - m##i); d##i += w_;                                   \
    _Pragma("unroll") for (int j = 0; j < 8; ++j) acc##i[j] += w_ * (float)SRC##i.v[j]; }

#define DECL_CHAIN(i)                                                           \
    int n##i = perm[base + i];                                                  \
    U8 xr##i; xr##i.v = *(const f16x8*)(xlr + (size_t)n##i * D2 + DCH + lane * 8); \
    int beg##i = row_ptr[n##i];                                                 \
    int deg##i = row_ptr[n##i + 1] - beg##i;                                    \
    int pre##i = (lane < deg##i) ? esrc[beg##i + lane] : 0;                     \
    float acc##i[8] = {}; float m##i = -FLT_MAX, d##i = 0.f;                    \
    U8 cA##i, cB##i;

#define EPI(i)                                                                  \
  { float inv = 1.f / d##i; f16x8 o;                                            \
    _Pragma("unroll")                                                           \
    for (int j = 0; j < 8; ++j) {                                               \
        float v = acc##i[j] * inv + bf[j];                                      \
        v = v > 0.f ? v : __expf(v) - 1.f;                                      \
        o[j] = (f16)v;                                                          \
    }                                                                           \
    *(f16x8*)(out + (size_t)n##i * DCH + lane * 8) = o; }

#define TLOAD(i, pp)                                                            \
  { int s_ = ((pp) < deg##i) ? esrc[beg##i + (pp)] : 0;                         \
    cA##i.v = *(const f16x8*)(xlr + (size_t)s_ * D2 + lane * 8); }

__global__ __launch_bounds__(256, 4) void edge_agg8(const int* __restrict__ row_ptr,
                                                    const int* __restrict__ esrc,
                                                    const int* __restrict__ perm,
                                                    const f16* __restrict__ xlr,
                                                    const float* __restrict__ att,
                                                    const float* __restrict__ bias,
                                                    f16* __restrict__ out) {
    int wv = (blockIdx.x * 256 + threadIdx.x) >> 6;
    int base = wv * 4;
    if (base >= N_NODES) return;            // N_NODES % 4 == 0
    int lane = threadIdx.x & 63;

    union U8 { f16x8 v; f16x2 q[4]; };
    const float4* av = (const float4*)(att + lane * 8);
    float4 a0 = av[0], a1 = av[1];
    f16x2 at2[4] = { f16x2{(f16)a0.x, (f16)a0.y}, f16x2{(f16)a0.z, (f16)a0.w},
                     f16x2{(f16)a1.x, (f16)a1.y}, f16x2{(f16)a1.z, (f16)a1.w} };
    const f16x2 k02 = {(f16)0.2f, (f16)0.2f};

    DECL_CHAIN(0) DECL_CHAIN(1) DECL_CHAIN(2) DECL_CHAIN(3)

    int dmax = max(max(deg0, deg1), max(deg2, deg3));
    int dcap = dmax < 64 ? dmax : 64;

    LOAD1(cA, 0, 0) LOAD1(cA, 1, 0) LOAD1(cA, 2, 0) LOAD1(cA, 3, 0)
    for (int p = 0; p < dcap; p += 2) {
        LOAD1(cB, 0, p + 1) LOAD1(cB, 1, p + 1) LOAD1(cB, 2, p + 1) LOAD1(cB, 3, p + 1)
        PROC1(cA, 0, p) PROC1(cA, 1, p) PROC1(cA, 2, p) PROC1(cA, 3, p)
        if (p + 1 >= dcap) break;
        LOAD1(cA, 0, p + 2) LOAD1(cA, 1, p + 2) LOAD1(cA, 2, p + 2) LOAD1(cA, 3, p + 2)
        PROC1(cB, 0, p + 1) PROC1(cB, 1, p + 1) PROC1(cB, 2, p + 1) PROC1(cB, 3, p + 1)
    }
    // rare tails: deg > 64 (LPT groups similar degree)
    for (int p = 64; p < dmax; ++p) {
        TLOAD(0, p) TLOAD(1, p) TLOAD(2, p) TLOAD(3, p)
        PROC1(cA, 0, p) PROC1(cA, 1, p) PROC1(cA, 2, p) PROC1(cA, 3, p)
    }

    const float4* bv = (const float4*)(bias + lane * 8);
    float4 b0 = bv[0], b1 = bv[1];
    float bf[8] = {b0.x, b0.y, b0.z, b0.w, b1.x, b1.y, b1.z, b1.w};
    EPI(0) EPI(1) EPI(2) EPI(3)
}

// ---------------- launch ----------------
extern "C" void kernel_launch(void* const* d_in, const int* in_sizes, int n_in,
                              void* d_out, int out_size, void* d_ws, size_t ws_size,
                              hipStream_t stream) {
    const float* x     = (const float*)d_in[0];
    const int*   ei    = (const int*)d_in[1];
    const float* w1_l  = (const float*)d_in[2];
    const float* b1_l  = (const float*)d_in[3];
    const float* w1_r  = (const float*)d_in[4];
    const float* b1_r  = (const float*)d_in[5];
    const float* att1  = (const float*)d_in[6];
    const float* bias1 = (const float*)d_in[7];
    const float* w2_l  = (const float*)d_in[8];
    const float* b2_l  = (const float*)d_in[9];
    const float* w2_r  = (const float*)d_in[10];
    const float* b2_r  = (const float*)d_in[11];
    const float* att2  = (const float*)d_in[12];
    const float* bias2 = (const float*)d_in[13];
    const float* wcls  = (const float*)d_in[14];
    const float* bcls  = (const float*)d_in[15];
    float* out = (float*)d_out;

    char* ws = (char*)d_ws;
    f16* x_h = (f16*)ws;                                    // N*64
    f16* w1T = x_h + (size_t)N_NODES * INCHP;               // 1024*64
    f16* w2T = w1T + (size_t)D2 * INCHP;                    // 1024*512
    f16* wcT = w2T + (size_t)D2 * DCH;                      // 128*512
    f16* xlr = wcT + (size_t)OUTCHP * DCH;                  // N*1024
    f16* h   = xlr + (size_t)N_NODES * D2;                  // N*512
    int* row_ptr = (int*)(h + (size_t)N_NODES * DCH);       // N+1
    int* counts  = row_ptr + (N_NODES + 1);                 // N   } contiguous
    int* cursor  = counts + N_NODES;                        // N   } zero pair
    int* esrc    = cursor + N_NODES;                        // ET
    int* perm    = esrc + ET;                               // N
    int* bbase   = perm + N_NODES;                          // NB
    int* bcur    = bbase + NB;                              // NB

    // 1. fused prep
    prep_all<<<5317, 256, 0, stream>>>(x, x_h, w1_l, w1_r, w2_l, w2_r, wcls,
                                       w1T, w2T, wcT, counts, bcur);
    // 2-4. CSR + LPT degree-sorted permutation
    count_kernel<<<(ET + 255) / 256, 256, 0, stream>>>(ei, counts);
    scan_kernel<<<1, 1024, 0, stream>>>(counts, row_ptr, bbase);
    fill_perm_kernel<<<ETB + NPB, 256, 0, stream>>>(ei, row_ptr, counts, bbase,
                                                    cursor, bcur, esrc, perm);

    dim3 blk(256);
    dim3 gD(D2 / 128, (N_NODES + 127) / 128);               // 8 x 157
    dim3 gC(1, (N_NODES + 127) / 128);
    int eb = (N_NODES / 4 + 3) / 4;                         // 4 nodes/wave

    // layer 1 (fused l|r, K=64)
    gemm_f16<1, 1><<<gD, blk, 0, stream>>>(x_h, w1T, b1_l, b1_r, xlr, N_NODES, INCHP, D2, D2);
    edge_agg8<<<eb, blk, 0, stream>>>(row_ptr, esrc, perm, xlr, att1, bias1, h);
    // layer 2 (fused l|r, K=512)
    gemm_f16<1, 1><<<gD, blk, 0, stream>>>(h, w2T, b2_l, b2_r, xlr, N_NODES, DCH, D2, D2);
    edge_agg8<<<eb, blk, 0, stream>>>(row_ptr, esrc, perm, xlr, att2, bias2, h);
    // classifier (N padded 128, fp32 out)
    gemm_f16<0, 0><<<gC, blk, 0, stream>>>(h, wcT, bcls, bcls, out, N_NODES, DCH, OUTCH, OUTCH);
}

// Round 10
// 255.342 us; speedup vs baseline: 1.1573x; 1.1573x over previous
//
#include <hip/hip_runtime.h>
#include <hip/hip_bf16.h>
#include <float.h>
#include <math.h>

#define N_NODES 20000
#define N_EDGES 320000
#define ET      (N_EDGES + N_NODES)   // edges + self loops
#define ETB     ((ET + 255) / 256)     // fill blocks
#define NPB     ((N_NODES + 255) / 256)// perm blocks
#define DCH     512
#define D2      1024                   // fused l|r width
#define INCH    55
#define INCHP   64
#define OUTCH   49
#define OUTCHP  128
#define NB      130                    // degree buckets (clamped)

typedef _Float16 f16;
typedef _Float16 f16x2 __attribute__((ext_vector_type(2)));
typedef _Float16 f16x4 __attribute__((ext_vector_type(4)));
typedef _Float16 f16x8 __attribute__((ext_vector_type(8)));
typedef float    f32x4 __attribute__((ext_vector_type(4)));

#define GPTR(p) ((const __attribute__((address_space(1))) void*)(p))
#define LPTR(p) ((__attribute__((address_space(3))) void*)(p))

// ---------------- fused prep: zeroing + conv_x + 5 weight transposes ----------
__device__ __forceinline__ void transpose_tile(const float* __restrict__ w, f16* __restrict__ o,
                                               int K, int N, int Kp, int bx, int by, int t,
                                               f16 (*tile)[66]) {
    int k0 = by * 64, n0 = bx * 64;
    #pragma unroll
    for (int r = 0; r < 16; ++r) {
        int kl = (t >> 6) + r * 4, nl = t & 63;
        int gk = k0 + kl, gn = n0 + nl;
        tile[kl][nl] = (gk < K && gn < N) ? (f16)w[(size_t)gk * N + gn] : (f16)0.f;
    }
    __syncthreads();
    #pragma unroll
    for (int r = 0; r < 16; ++r) {
        int kl = t & 63, nl = (t >> 6) + r * 4;
        o[(size_t)(n0 + nl) * Kp + k0 + kl] = tile[kl][nl];
    }
}

__global__ __launch_bounds__(256) void prep_all(const float* __restrict__ x, f16* __restrict__ x_h,
                                                const float* __restrict__ w1l, const float* __restrict__ w1r,
                                                const float* __restrict__ w2l, const float* __restrict__ w2r,
                                                const float* __restrict__ wc,
                                                f16* __restrict__ w1T, f16* __restrict__ w2T,
                                                f16* __restrict__ wcT,
                                                int* __restrict__ zeroA,   // counts+cursor contiguous (40000)
                                                int* __restrict__ bcur) {
    __shared__ f16 tile[64][66];
    int b = blockIdx.x, t = threadIdx.x;
    if (b < 157) {
        int i = b * 256 + t;
        if (i < 40000) zeroA[i] = 0;
        else if (i < 40000 + NB) bcur[i - 40000] = 0;
        return;
    }
    b -= 157;
    if (b < 5000) {
        int i = b * 256 + t;
        int r = i >> 6, c = i & 63;
        x_h[i] = (c < INCH) ? (f16)x[r * INCH + c] : (f16)0.f;
        return;
    }
    b -= 5000;
    if (b < 8)  { transpose_tile(w1l, w1T, INCH, DCH, INCHP, b, 0, t, tile); return; }
    b -= 8;
    if (b < 8)  { transpose_tile(w1r, w1T + (size_t)DCH * INCHP, INCH, DCH, INCHP, b, 0, t, tile); return; }
    b -= 8;
    if (b < 64) { transpose_tile(w2l, w2T, DCH, DCH, DCH, b & 7, b >> 3, t, tile); return; }
    b -= 64;
    if (b < 64) { transpose_tile(w2r, w2T + (size_t)DCH * DCH, DCH, DCH, DCH, b & 7, b >> 3, t, tile); return; }
    b -= 64;
    transpose_tile(wc, wcT, DCH, OUTCH, DCH, b & 1, b >> 1, t, tile);
}

// ---------------- CSR build (by dst) ----------------
__global__ void count_kernel(const int* __restrict__ ei, int* __restrict__ counts) {
    int e = blockIdx.x * blockDim.x + threadIdx.x;
    if (e >= ET) return;
    int d = (e < N_EDGES) ? ei[N_EDGES + e] : (e - N_EDGES);
    atomicAdd(&counts[d], 1);
}

// node prefix-sum + degree-bucket histogram + DESCENDING bucket prefix (LPT)
__global__ void scan_kernel(const int* __restrict__ counts, int* __restrict__ row_ptr,
                            int* __restrict__ bbase) {
    __shared__ int sdata[1024];
    __shared__ int bh[NB];
    int t = threadIdx.x;
    if (t < NB) bh[t] = 0;
    __syncthreads();
    int per = (N_NODES + 1023) / 1024;
    int b = t * per, e = min(N_NODES, b + per);
    int sum = 0;
    for (int i = b; i < e; ++i) {
        int c = counts[i];
        sum += c;
        atomicAdd(&bh[min(c, NB - 1)], 1);
    }
    sdata[t] = sum;
    __syncthreads();
    for (int off = 1; off < 1024; off <<= 1) {
        int v = (t >= off) ? sdata[t - off] : 0;
        __syncthreads();
        sdata[t] += v;
        __syncthreads();
    }
    int run = (t == 0) ? 0 : sdata[t - 1];
    if (t == 0) row_ptr[0] = 0;
    for (int i = b; i < e; ++i) { run += counts[i]; row_ptr[i + 1] = run; }
    __syncthreads();
    if (t == 0) {
        int acc = 0;
        for (int j = NB - 1; j >= 0; --j) { bbase[j] = acc; acc += bh[j]; }  // LPT
    }
}

// fill CSR + degree-bucket scatter (hierarchical atomics). Intra-bucket order
// schedule-dependent; per-node outputs independent -> d_out deterministic.
__global__ __launch_bounds__(256) void fill_perm_kernel(const int* __restrict__ ei,
                                                        const int* __restrict__ row_ptr,
                                                        const int* __restrict__ counts,
                                                        const int* __restrict__ bbase,
                                                        int* __restrict__ cursor,
                                                        int* __restrict__ bcur,
                                                        int* __restrict__ esrc,
                                                        int* __restrict__ perm) {
    int blk = blockIdx.x;
    if (blk < ETB) {                        // CSR fill segment
        int e = blk * 256 + threadIdx.x;
        if (e >= ET) return;
        int s, d;
        if (e < N_EDGES) { s = ei[e]; d = ei[N_EDGES + e]; }
        else             { s = d = e - N_EDGES; }
        int pos = row_ptr[d] + atomicAdd(&cursor[d], 1);
        esrc[pos] = s;
        return;
    }
    blk -= ETB;
    __shared__ int hist[NB], basep[NB];
    int t = threadIdx.x;
    for (int i = t; i < NB; i += 256) hist[i] = 0;
    __syncthreads();
    int n = blk * 256 + t;
    bool valid = n < N_NODES;
    int bkt = 0, rl = 0;
    if (valid) {
        bkt = min(counts[n], NB - 1);
        rl = atomicAdd(&hist[bkt], 1);
    }
    __syncthreads();
    for (int i = t; i < NB; i += 256)
        if (hist[i] > 0) basep[i] = atomicAdd(&bcur[i], hist[i]);
    __syncthreads();
    if (valid) perm[bbase[bkt] + basep[bkt] + rl] = n;
}

// ---------------- fp16 MFMA GEMM (BK=64, T2 XOR swizzle, T1 XCD swizzle) --------
// OPERAND-SWAP epilogue: mfma(bf, af, acc) -> lane owns fixed M-row (lane&15)
// and 4 CONSECUTIVE N-cols ((lane>>4)*4 + r) -> f16x4 vector stores (16x8B
// instead of 64x2B scalar). DUAL bias boundary (512) is 4-aligned, never
// straddled by a run.
template<int OUT_F16, int DUAL>
__global__ __launch_bounds__(256) void gemm_f16(const f16* __restrict__ A,
                                                const f16* __restrict__ BT,
                                                const float* __restrict__ bl,
                                                const float* __restrict__ br,
                                                void* __restrict__ Cout,
                                                int M, int Ka, int Nv, int ldc) {
    __shared__ __align__(16) f16 As[128][64];
    __shared__ __align__(16) f16 Bs[128][64];
    const int tid = threadIdx.x;
    const int w = tid >> 6, lane = tid & 63;
    int nbx = gridDim.x;
    int nwg = nbx * gridDim.y;
    int bid = blockIdx.y * nbx + blockIdx.x;
    if ((nwg & 7) == 0) bid = (bid & 7) * (nwg >> 3) + (bid >> 3);   // XCD swizzle (T1)
    const int m0 = (bid / nbx) * 128, n0 = (bid % nbx) * 128;
    const int wr = (w >> 1) * 64, wc = (w & 1) * 64;
    const int lrow = lane & 15, lk = lane >> 4;
    const int sw = lrow & 7;

    f32x4 acc[4][4] = {};

    for (int k0 = 0; k0 < Ka; k0 += 64) {
        #pragma unroll
        for (int i = 0; i < 4; ++i) {
            int idx = tid + 256 * i;
            int row = idx >> 3;
            int cg  = (idx & 7) ^ (row & 7);
            int gm = m0 + row; gm = gm < M ? gm : M - 1;
            const f16* gp = A + (size_t)gm * Ka + k0 + cg * 8;
            f16* lp = &As[0][0] + (size_t)(w * 64 + 256 * i) * 8;
            __builtin_amdgcn_global_load_lds(GPTR(gp), LPTR(lp), 16, 0, 0);
        }
        #pragma unroll
        for (int i = 0; i < 4; ++i) {
            int idx = tid + 256 * i;
            int row = idx >> 3;
            int cg  = (idx & 7) ^ (row & 7);
            const f16* gp = BT + (size_t)(n0 + row) * Ka + k0 + cg * 8;
            f16* lp = &Bs[0][0] + (size_t)(w * 64 + 256 * i) * 8;
            __builtin_amdgcn_global_load_lds(GPTR(gp), LPTR(lp), 16, 0, 0);
        }
        __syncthreads();
        #pragma unroll
        for (int kk = 0; kk < 64; kk += 32) {
            f16x8 af[4], bf[4];
            #pragma unroll
            for (int m = 0; m < 4; ++m)
                af[m] = *(const f16x8*)&As[wr + m * 16 + lrow][(((kk >> 3) + lk) ^ sw) * 8];
            #pragma unroll
            for (int n = 0; n < 4; ++n)
                bf[n] = *(const f16x8*)&Bs[wc + n * 16 + lrow][(((kk >> 3) + lk) ^ sw) * 8];
            #pragma unroll
            for (int m = 0; m < 4; ++m)
                #pragma unroll
                for (int n = 0; n < 4; ++n)
                    acc[m][n] = __builtin_amdgcn_mfma_f32_16x16x32_f16(bf[n], af[m], acc[m][n], 0, 0, 0);
        }
        __syncthreads();
    }

    // swapped C/D map: col(lane&15) -> m, row-group((lane>>4)*4+r) -> n
    const int om = lane & 15, on4 = (lane >> 4) * 4;
    #pragma unroll
    for (int nn = 0; nn < 4; ++nn) {
        int gn0 = n0 + wc + nn * 16 + on4;
        if (OUT_F16) {
            const float* bp = (DUAL && gn0 >= DCH) ? (br + gn0 - DCH) : (bl + gn0);
            float4 bv = *(const float4*)bp;
            float bfr[4] = {bv.x, bv.y, bv.z, bv.w};
            #pragma unroll
            for (int mm = 0; mm < 4; ++mm) {
                int gm = m0 + wr + mm * 16 + om;
                if (gm >= M) continue;
                f16x4 o;
                #pragma unroll
                for (int r = 0; r < 4; ++r) o[r] = (f16)(acc[mm][nn][r] + bfr[r]);
                *(f16x4*)((f16*)Cout + (size_t)gm * ldc + gn0) = o;
            }
        } else {
            #pragma unroll
            for (int mm = 0; mm < 4; ++mm) {
                int gm = m0 + wr + mm * 16 + om;
                if (gm >= M) continue;
                #pragma unroll
                for (int r = 0; r < 4; ++r) {
                    int gn = gn0 + r;
                    if (gn < Nv) ((float*)Cout)[(size_t)gm * ldc + gn] = acc[mm][nn][r] + bl[gn];
                }
            }
        }
    }
}

// ---------------- fused GATv2 edge phase v9 ----------------
// Two degree-matched nodes per wave (LPT perm); 3-buffer lookahead-2 gather
// pipeline; f16x2 packed accumulate (v_pk_fma_f16) with defer-max THR=2
// (w <= e^2 -> acc bounded, f16-safe); f16-rounded w used for BOTH acc and den.
#define PROC(cc0, cc1, pp)                                                      \
  {                                                                             \
    float sc0 = 0.f, sc1 = 0.f;                                                 \
    _Pragma("unroll")                                                           \
    for (int j = 0; j < 4; ++j) {                                               \
        f16x2 u0 = cc0.q[j] + xr0.q[j];                                         \
        f16x2 u1 = cc1.q[j] + xr1.q[j];                                         \
        f16x2 l0 = __builtin_elementwise_max(u0, u0 * k02);                     \
        f16x2 l1 = __builtin_elementwise_max(u1, u1 * k02);                     \
        sc0 = __builtin_amdgcn_fdot2(l0, at2[j], sc0, false);                   \
        sc1 = __builtin_amdgcn_fdot2(l1, at2[j], sc1, false);                   \
    }                                                                           \
    _Pragma("unroll")                                                           \
    for (int o = 8; o >= 1; o >>= 1) {                                          \
        sc0 += __shfl_xor(sc0, o, 64);                                          \
        sc1 += __shfl_xor(sc1, o, 64);                                          \
    }                                                                           \
    if ((pp) >= deg0) sc0 = -INFINITY;                                          \
    if ((pp) >= deg1) sc1 = -INFINITY;                                          \
    if (__any(sc0 > m0 + 2.f)) {                                                \
        float mn = fmaxf(m0, sc0);                                              \
        f16 fh = (f16)__expf(m0 - mn);                                          \
        f16x2 fh2 = {fh, fh};                                                   \
        d0 *= (float)fh;                                                        \
        _Pragma("unroll") for (int j = 0; j < 4; ++j) acc0.q[j] *= fh2;         \
        m0 = mn;                                                                \
    }                                                                           \
    { f16 wh = (f16)__expf(sc0 - m0); d0 += (float)wh;                          \
      f16x2 wh2 = {wh, wh};                                                     \
      _Pragma("unroll") for (int j = 0; j < 4; ++j)                             \
          acc0.q[j] += wh2 * cc0.q[j]; }                                        \
    if (__any(sc1 > m1 + 2.f)) {                                                \
        float mn = fmaxf(m1, sc1);                                              \
        f16 fh = (f16)__expf(m1 - mn);                                          \
        f16x2 fh2 = {fh, fh};                                                   \
        d1 *= (float)fh;                                                        \
        _Pragma("unroll") for (int j = 0; j < 4; ++j) acc1.q[j] *= fh2;         \
        m1 = mn;                                                                \
    }                                                                           \
    { f16 wh = (f16)__expf(sc1 - m1); d1 += (float)wh;                          \
      f16x2 wh2 = {wh, wh};                                                     \
      _Pragma("unroll") for (int j = 0; j < 4; ++j)                             \
          acc1.q[j] += wh2 * cc1.q[j]; }                                        \
  }

#define LOADU(B0, B1, pp)                                                       \
  {                                                                             \
    int q = (pp) < dcap ? (pp) : dcap - 1;                                      \
    int s0 = __shfl(pre0, q, 64), s1 = __shfl(pre1, q, 64);                     \
    B0.v = *(const f16x8*)(xlr + (size_t)s0 * D2 + lane * 8);                   \
    B1.v = *(const f16x8*)(xlr + (size_t)s1 * D2 + lane * 8);                   \
  }

__global__ __launch_bounds__(256) void edge_agg9(const int* __restrict__ row_ptr,
                                                 const int* __restrict__ esrc,
                                                 const int* __restrict__ perm,
                                                 const f16* __restrict__ xlr,
                                                 const float* __restrict__ att,
                                                 const float* __restrict__ bias,
                                                 f16* __restrict__ out) {
    int wv = (blockIdx.x * 256 + threadIdx.x) >> 6;
    if (wv * 2 >= N_NODES) return;
    int n0 = perm[wv * 2], n1 = perm[wv * 2 + 1];
    int lane = threadIdx.x & 63;

    union U8 { f16x8 v; f16x2 q[4]; };
    U8 xr0, xr1;
    xr0.v = *(const f16x8*)(xlr + (size_t)n0 * D2 + DCH + lane * 8);
    xr1.v = *(const f16x8*)(xlr + (size_t)n1 * D2 + DCH + lane * 8);
    const float4* av = (const float4*)(att + lane * 8);
    float4 a0 = av[0], a1 = av[1];
    f16x2 at2[4] = { f16x2{(f16)a0.x, (f16)a0.y}, f16x2{(f16)a0.z, (f16)a0.w},
                     f16x2{(f16)a1.x, (f16)a1.y}, f16x2{(f16)a1.z, (f16)a1.w} };
    const f16x2 k02 = {(f16)0.2f, (f16)0.2f};

    int beg0 = row_ptr[n0], deg0 = row_ptr[n0 + 1] - beg0;
    int beg1 = row_ptr[n1], deg1 = row_ptr[n1 + 1] - beg1;
    int pre0 = (lane < deg0) ? esrc[beg0 + lane] : 0;
    int pre1 = (lane < deg1) ? esrc[beg1 + lane] : 0;

    U8 acc0, acc1;
    acc0.v = (f16x8)(f16)0.f;
    acc1.v = (f16x8)(f16)0.f;
    float m0 = -FLT_MAX, m1 = -FLT_MAX, d0 = 0.f, d1 = 0.f;

    int dmax = deg0 > deg1 ? deg0 : deg1;
    int dcap = dmax < 64 ? dmax : 64;

    U8 cA0, cA1, cB0, cB1, cC0, cC1;
    LOADU(cA0, cA1, 0)
    LOADU(cB0, cB1, 1)
    for (int p = 0; p < dcap; p += 3) {      // unroll-3 rotation, static names
        LOADU(cC0, cC1, p + 2)
        PROC(cA0, cA1, p)
        if (p + 1 >= dcap) break;
        LOADU(cA0, cA1, p + 3)
        PROC(cB0, cB1, p + 1)
        if (p + 2 >= dcap) break;
        LOADU(cB0, cB1, p + 4)
        PROC(cC0, cC1, p + 2)
    }
    // rare tails: deg > 64 (LPT pairs similar degree)
    for (int p = 64; p < dmax; ++p) {
        int s0 = (p < deg0) ? esrc[beg0 + p] : 0;
        int s1 = (p < deg1) ? esrc[beg1 + p] : 0;
        U8 t0, t1;
        t0.v = *(const f16x8*)(xlr + (size_t)s0 * D2 + lane * 8);
        t1.v = *(const f16x8*)(xlr + (size_t)s1 * D2 + lane * 8);
        PROC(t0, t1, p)
    }

    const float4* bv = (const float4*)(bias + lane * 8);
    float4 b0 = bv[0], b1 = bv[1];
    float bf[8] = {b0.x, b0.y, b0.z, b0.w, b1.x, b1.y, b1.z, b1.w};
    float i0 = 1.f / d0, i1 = 1.f / d1;
    f16x8 o0, o1;
    #pragma unroll
    for (int j = 0; j < 8; ++j) {
        float v0 = (float)acc0.v[j] * i0 + bf[j];
        float v1 = (float)acc1.v[j] * i1 + bf[j];
        v0 = v0 > 0.f ? v0 : __expf(v0) - 1.f;   // ELU
        v1 = v1 > 0.f ? v1 : __expf(v1) - 1.f;
        o0[j] = (f16)v0;
        o1[j] = (f16)v1;
    }
    *(f16x8*)(out + (size_t)n0 * DCH + lane * 8) = o0;
    *(f16x8*)(out + (size_t)n1 * DCH + lane * 8) = o1;
}

// ---------------- launch ----------------
extern "C" void kernel_launch(void* const* d_in, const int* in_sizes, int n_in,
                              void* d_out, int out_size, void* d_ws, size_t ws_size,
                              hipStream_t stream) {
    const float* x     = (const float*)d_in[0];
    const int*   ei    = (const int*)d_in[1];
    const float* w1_l  = (const float*)d_in[2];
    const float* b1_l  = (const float*)d_in[3];
    const float* w1_r  = (const float*)d_in[4];
    const float* b1_r  = (const float*)d_in[5];
    const float* att1  = (const float*)d_in[6];
    const float* bias1 = (const float*)d_in[7];
    const float* w2_l  = (const float*)d_in[8];
    const float* b2_l  = (const float*)d_in[9];
    const float* w2_r  = (const float*)d_in[10];
    const float* b2_r  = (const float*)d_in[11];
    const float* att2  = (const float*)d_in[12];
    const float* bias2 = (const float*)d_in[13];
    const float* wcls  = (const float*)d_in[14];
    const float* bcls  = (const float*)d_in[15];
    float* out = (float*)d_out;

    char* ws = (char*)d_ws;
    f16* x_h = (f16*)ws;                                    // N*64
    f16* w1T = x_h + (size_t)N_NODES * INCHP;               // 1024*64
    f16* w2T = w1T + (size_t)D2 * INCHP;                    // 1024*512
    f16* wcT = w2T + (size_t)D2 * DCH;                      // 128*512
    f16* xlr = wcT + (size_t)OUTCHP * DCH;                  // N*1024
    f16* h   = xlr + (size_t)N_NODES * D2;                  // N*512
    int* row_ptr = (int*)(h + (size_t)N_NODES * DCH);       // N+1
    int* counts  = row_ptr + (N_NODES + 1);                 // N   } contiguous
    int* cursor  = counts + N_NODES;                        // N   } zero pair
    int* esrc    = cursor + N_NODES;                        // ET
    int* perm    = esrc + ET;                               // N
    int* bbase   = perm + N_NODES;                          // NB
    int* bcur    = bbase + NB;                              // NB

    // 1. fused prep
    prep_all<<<5317, 256, 0, stream>>>(x, x_h, w1_l, w1_r, w2_l, w2_r, wcls,
                                       w1T, w2T, wcT, counts, bcur);
    // 2-4. CSR + LPT degree-sorted permutation
    count_kernel<<<(ET + 255) / 256, 256, 0, stream>>>(ei, counts);
    scan_kernel<<<1, 1024, 0, stream>>>(counts, row_ptr, bbase);
    fill_perm_kernel<<<ETB + NPB, 256, 0, stream>>>(ei, row_ptr, counts, bbase,
                                                    cursor, bcur, esrc, perm);

    dim3 blk(256);
    dim3 gD(D2 / 128, (N_NODES + 127) / 128);               // 8 x 157
    dim3 gC(1, (N_NODES + 127) / 128);
    int eb = (N_NODES / 2 + 3) / 4;                         // 2 nodes/wave

    // layer 1 (fused l|r, K=64)
    gemm_f16<1, 1><<<gD, blk, 0, stream>>>(x_h, w1T, b1_l, b1_r, xlr, N_NODES, INCHP, D2, D2);
    edge_agg9<<<eb, blk, 0, stream>>>(row_ptr, esrc, perm, xlr, att1, bias1, h);
    // layer 2 (fused l|r, K=512)
    gemm_f16<1, 1><<<gD, blk, 0, stream>>>(h, w2T, b2_l, b2_r, xlr, N_NODES, DCH, D2, D2);
    edge_agg9<<<eb, blk, 0, stream>>>(row_ptr, esrc, perm, xlr, att2, bias2, h);
    // classifier (N padded 128, fp32 out)
    gemm_f16<0, 0><<<gC, blk, 0, stream>>>(h, wcT, bcls, bcls, out, N_NODES, DCH, OUTCH, OUTCH);
}

// Round 11
// 255.276 us; speedup vs baseline: 1.1576x; 1.0003x over previous
//
#include <hip/hip_runtime.h>
#include <hip/hip_bf16.h>
#include <float.h>
#include <math.h>

#define N_NODES 20000
#define N_EDGES 320000
#define ET      (N_EDGES + N_NODES)   // edges + self loops
#define ETB     ((ET + 255) / 256)     // fill blocks
#define NPB     ((N_NODES + 255) / 256)// perm blocks
#define DCH     512
#define D2      1024                   // fused l|r width
#define INCH    55
#define INCHP   64
#define OUTCH   49
#define OUTCHP  128
#define NB      130                    // degree buckets (clamped)

typedef _Float16 f16;
typedef _Float16 f16x2 __attribute__((ext_vector_type(2)));
typedef _Float16 f16x4 __attribute__((ext_vector_type(4)));
typedef _Float16 f16x8 __attribute__((ext_vector_type(8)));
typedef float    f32x4 __attribute__((ext_vector_type(4)));

#define GPTR(p) ((const __attribute__((address_space(1))) void*)(p))
#define LPTR(p) ((__attribute__((address_space(3))) void*)(p))

// ---------------- fused prep: zeroing + conv_x + 5 weight transposes ----------
__device__ __forceinline__ void transpose_tile(const float* __restrict__ w, f16* __restrict__ o,
                                               int K, int N, int Kp, int bx, int by, int t,
                                               f16 (*tile)[66]) {
    int k0 = by * 64, n0 = bx * 64;
    #pragma unroll
    for (int r = 0; r < 16; ++r) {
        int kl = (t >> 6) + r * 4, nl = t & 63;
        int gk = k0 + kl, gn = n0 + nl;
        tile[kl][nl] = (gk < K && gn < N) ? (f16)w[(size_t)gk * N + gn] : (f16)0.f;
    }
    __syncthreads();
    #pragma unroll
    for (int r = 0; r < 16; ++r) {
        int kl = t & 63, nl = (t >> 6) + r * 4;
        o[(size_t)(n0 + nl) * Kp + k0 + kl] = tile[kl][nl];
    }
}

__global__ __launch_bounds__(256) void prep_all(const float* __restrict__ x, f16* __restrict__ x_h,
                                                const float* __restrict__ w1l, const float* __restrict__ w1r,
                                                const float* __restrict__ w2l, const float* __restrict__ w2r,
                                                const float* __restrict__ wc,
                                                f16* __restrict__ w1T, f16* __restrict__ w2T,
                                                f16* __restrict__ wcT,
                                                int* __restrict__ zeroA,   // counts+cursor contiguous (40000)
                                                int* __restrict__ bcur) {
    __shared__ f16 tile[64][66];
    int b = blockIdx.x, t = threadIdx.x;
    if (b < 157) {
        int i = b * 256 + t;
        if (i < 40000) zeroA[i] = 0;
        else if (i < 40000 + NB) bcur[i - 40000] = 0;
        return;
    }
    b -= 157;
    if (b < 5000) {
        int i = b * 256 + t;
        int r = i >> 6, c = i & 63;
        x_h[i] = (c < INCH) ? (f16)x[r * INCH + c] : (f16)0.f;
        return;
    }
    b -= 5000;
    if (b < 8)  { transpose_tile(w1l, w1T, INCH, DCH, INCHP, b, 0, t, tile); return; }
    b -= 8;
    if (b < 8)  { transpose_tile(w1r, w1T + (size_t)DCH * INCHP, INCH, DCH, INCHP, b, 0, t, tile); return; }
    b -= 8;
    if (b < 64) { transpose_tile(w2l, w2T, DCH, DCH, DCH, b & 7, b >> 3, t, tile); return; }
    b -= 64;
    if (b < 64) { transpose_tile(w2r, w2T + (size_t)DCH * DCH, DCH, DCH, DCH, b & 7, b >> 3, t, tile); return; }
    b -= 64;
    transpose_tile(wc, wcT, DCH, OUTCH, DCH, b & 1, b >> 1, t, tile);
}

// ---------------- CSR build (by dst) ----------------
__global__ void count_kernel(const int* __restrict__ ei, int* __restrict__ counts) {
    int e = blockIdx.x * blockDim.x + threadIdx.x;
    if (e >= ET) return;
    int d = (e < N_EDGES) ? ei[N_EDGES + e] : (e - N_EDGES);
    atomicAdd(&counts[d], 1);
}

// node prefix-sum + degree-bucket histogram + DESCENDING bucket prefix (LPT)
__global__ void scan_kernel(const int* __restrict__ counts, int* __restrict__ row_ptr,
                            int* __restrict__ bbase) {
    __shared__ int sdata[1024];
    __shared__ int bh[NB];
    int t = threadIdx.x;
    if (t < NB) bh[t] = 0;
    __syncthreads();
    int per = (N_NODES + 1023) / 1024;
    int b = t * per, e = min(N_NODES, b + per);
    int sum = 0;
    for (int i = b; i < e; ++i) {
        int c = counts[i];
        sum += c;
        atomicAdd(&bh[min(c, NB - 1)], 1);
    }
    sdata[t] = sum;
    __syncthreads();
    for (int off = 1; off < 1024; off <<= 1) {
        int v = (t >= off) ? sdata[t - off] : 0;
        __syncthreads();
        sdata[t] += v;
        __syncthreads();
    }
    int run = (t == 0) ? 0 : sdata[t - 1];
    if (t == 0) row_ptr[0] = 0;
    for (int i = b; i < e; ++i) { run += counts[i]; row_ptr[i + 1] = run; }
    __syncthreads();
    if (t == 0) {
        int acc = 0;
        for (int j = NB - 1; j >= 0; --j) { bbase[j] = acc; acc += bh[j]; }  // LPT
    }
}

// fill CSR + degree-bucket scatter (hierarchical atomics). Intra-bucket order
// schedule-dependent; per-node outputs independent -> d_out deterministic.
__global__ __launch_bounds__(256) void fill_perm_kernel(const int* __restrict__ ei,
                                                        const int* __restrict__ row_ptr,
                                                        const int* __restrict__ counts,
                                                        const int* __restrict__ bbase,
                                                        int* __restrict__ cursor,
                                                        int* __restrict__ bcur,
                                                        int* __restrict__ esrc,
                                                        int* __restrict__ perm) {
    int blk = blockIdx.x;
    if (blk < ETB) {                        // CSR fill segment
        int e = blk * 256 + threadIdx.x;
        if (e >= ET) return;
        int s, d;
        if (e < N_EDGES) { s = ei[e]; d = ei[N_EDGES + e]; }
        else             { s = d = e - N_EDGES; }
        int pos = row_ptr[d] + atomicAdd(&cursor[d], 1);
        esrc[pos] = s;
        return;
    }
    blk -= ETB;
    __shared__ int hist[NB], basep[NB];
    int t = threadIdx.x;
    for (int i = t; i < NB; i += 256) hist[i] = 0;
    __syncthreads();
    int n = blk * 256 + t;
    bool valid = n < N_NODES;
    int bkt = 0, rl = 0;
    if (valid) {
        bkt = min(counts[n], NB - 1);
        rl = atomicAdd(&hist[bkt], 1);
    }
    __syncthreads();
    for (int i = t; i < NB; i += 256)
        if (hist[i] > 0) basep[i] = atomicAdd(&bcur[i], hist[i]);
    __syncthreads();
    if (valid) perm[bbase[bkt] + basep[bkt] + rl] = n;
}

// ---------------- fp16 MFMA GEMM (BK=64, T2 XOR swizzle, T1 XCD swizzle) --------
// OPERAND-SWAP epilogue: mfma(bf, af, acc) -> lane owns fixed M-row (lane&15)
// and 4 CONSECUTIVE N-cols -> f16x4 vector stores.
template<int OUT_F16, int DUAL>
__global__ __launch_bounds__(256) void gemm_f16(const f16* __restrict__ A,
                                                const f16* __restrict__ BT,
                                                const float* __restrict__ bl,
                                                const float* __restrict__ br,
                                                void* __restrict__ Cout,
                                                int M, int Ka, int Nv, int ldc) {
    __shared__ __align__(16) f16 As[128][64];
    __shared__ __align__(16) f16 Bs[128][64];
    const int tid = threadIdx.x;
    const int w = tid >> 6, lane = tid & 63;
    int nbx = gridDim.x;
    int nwg = nbx * gridDim.y;
    int bid = blockIdx.y * nbx + blockIdx.x;
    if ((nwg & 7) == 0) bid = (bid & 7) * (nwg >> 3) + (bid >> 3);   // XCD swizzle (T1)
    const int m0 = (bid / nbx) * 128, n0 = (bid % nbx) * 128;
    const int wr = (w >> 1) * 64, wc = (w & 1) * 64;
    const int lrow = lane & 15, lk = lane >> 4;
    const int sw = lrow & 7;

    f32x4 acc[4][4] = {};

    for (int k0 = 0; k0 < Ka; k0 += 64) {
        #pragma unroll
        for (int i = 0; i < 4; ++i) {
            int idx = tid + 256 * i;
            int row = idx >> 3;
            int cg  = (idx & 7) ^ (row & 7);
            int gm = m0 + row; gm = gm < M ? gm : M - 1;
            const f16* gp = A + (size_t)gm * Ka + k0 + cg * 8;
            f16* lp = &As[0][0] + (size_t)(w * 64 + 256 * i) * 8;
            __builtin_amdgcn_global_load_lds(GPTR(gp), LPTR(lp), 16, 0, 0);
        }
        #pragma unroll
        for (int i = 0; i < 4; ++i) {
            int idx = tid + 256 * i;
            int row = idx >> 3;
            int cg  = (idx & 7) ^ (row & 7);
            const f16* gp = BT + (size_t)(n0 + row) * Ka + k0 + cg * 8;
            f16* lp = &Bs[0][0] + (size_t)(w * 64 + 256 * i) * 8;
            __builtin_amdgcn_global_load_lds(GPTR(gp), LPTR(lp), 16, 0, 0);
        }
        __syncthreads();
        #pragma unroll
        for (int kk = 0; kk < 64; kk += 32) {
            f16x8 af[4], bf[4];
            #pragma unroll
            for (int m = 0; m < 4; ++m)
                af[m] = *(const f16x8*)&As[wr + m * 16 + lrow][(((kk >> 3) + lk) ^ sw) * 8];
            #pragma unroll
            for (int n = 0; n < 4; ++n)
                bf[n] = *(const f16x8*)&Bs[wc + n * 16 + lrow][(((kk >> 3) + lk) ^ sw) * 8];
            #pragma unroll
            for (int m = 0; m < 4; ++m)
                #pragma unroll
                for (int n = 0; n < 4; ++n)
                    acc[m][n] = __builtin_amdgcn_mfma_f32_16x16x32_f16(bf[n], af[m], acc[m][n], 0, 0, 0);
        }
        __syncthreads();
    }

    // swapped C/D map: col(lane&15) -> m, row-group((lane>>4)*4+r) -> n
    const int om = lane & 15, on4 = (lane >> 4) * 4;
    #pragma unroll
    for (int nn = 0; nn < 4; ++nn) {
        int gn0 = n0 + wc + nn * 16 + on4;
        if (OUT_F16) {
            const float* bp = (DUAL && gn0 >= DCH) ? (br + gn0 - DCH) : (bl + gn0);
            float4 bv = *(const float4*)bp;
            float bfr[4] = {bv.x, bv.y, bv.z, bv.w};
            #pragma unroll
            for (int mm = 0; mm < 4; ++mm) {
                int gm = m0 + wr + mm * 16 + om;
                if (gm >= M) continue;
                f16x4 o;
                #pragma unroll
                for (int r = 0; r < 4; ++r) o[r] = (f16)(acc[mm][nn][r] + bfr[r]);
                *(f16x4*)((f16*)Cout + (size_t)gm * ldc + gn0) = o;
            }
        } else {
            #pragma unroll
            for (int mm = 0; mm < 4; ++mm) {
                int gm = m0 + wr + mm * 16 + om;
                if (gm >= M) continue;
                #pragma unroll
                for (int r = 0; r < 4; ++r) {
                    int gn = gn0 + r;
                    if (gn < Nv) ((float*)Cout)[(size_t)gm * ldc + gn] = acc[mm][nn][r] + bl[gn];
                }
            }
        }
    }
}

// ---------------- fused GATv2 edge phase v10 ----------------
// Two degree-matched nodes per wave (LPT perm); RING-4 / LOOKAHEAD-3 gather
// pipeline (edge p+3's rows issued ~3 PROCs (~500cyc) before consumption —
// R10 showed lookahead-2 leaves ~50% memory stall); f16x2 packed accumulate
// (defer-max THR=2, f16-rounded w for both acc and den).
#define PROC(cc0, cc1, pp)                                                      \
  {                                                                             \
    float sc0 = 0.f, sc1 = 0.f;                                                 \
    _Pragma("unroll")                                                           \
    for (int j = 0; j < 4; ++j) {                                               \
        f16x2 u0 = cc0.q[j] + xr0.q[j];                                         \
        f16x2 u1 = cc1.q[j] + xr1.q[j];                                         \
        f16x2 l0 = __builtin_elementwise_max(u0, u0 * k02);                     \
        f16x2 l1 = __builtin_elementwise_max(u1, u1 * k02);                     \
        sc0 = __builtin_amdgcn_fdot2(l0, at2[j], sc0, false);                   \
        sc1 = __builtin_amdgcn_fdot2(l1, at2[j], sc1, false);                   \
    }                                                                           \
    _Pragma("unroll")                                                           \
    for (int o = 8; o >= 1; o >>= 1) {                                          \
        sc0 += __shfl_xor(sc0, o, 64);                                          \
        sc1 += __shfl_xor(sc1, o, 64);                                          \
    }                                                                           \
    if ((pp) >= deg0) sc0 = -INFINITY;                                          \
    if ((pp) >= deg1) sc1 = -INFINITY;                                          \
    if (__any(sc0 > m0 + 2.f)) {                                                \
        float mn = fmaxf(m0, sc0);                                              \
        f16 fh = (f16)__expf(m0 - mn);                                          \
        f16x2 fh2 = {fh, fh};                                                   \
        d0 *= (float)fh;                                                        \
        _Pragma("unroll") for (int j = 0; j < 4; ++j) acc0.q[j] *= fh2;         \
        m0 = mn;                                                                \
    }                                                                           \
    { f16 wh = (f16)__expf(sc0 - m0); d0 += (float)wh;                          \
      f16x2 wh2 = {wh, wh};                                                     \
      _Pragma("unroll") for (int j = 0; j < 4; ++j)                             \
          acc0.q[j] += wh2 * cc0.q[j]; }                                        \
    if (__any(sc1 > m1 + 2.f)) {                                                \
        float mn = fmaxf(m1, sc1);                                              \
        f16 fh = (f16)__expf(m1 - mn);                                          \
        f16x2 fh2 = {fh, fh};                                                   \
        d1 *= (float)fh;                                                        \
        _Pragma("unroll") for (int j = 0; j < 4; ++j) acc1.q[j] *= fh2;         \
        m1 = mn;                                                                \
    }                                                                           \
    { f16 wh = (f16)__expf(sc1 - m1); d1 += (float)wh;                          \
      f16x2 wh2 = {wh, wh};                                                     \
      _Pragma("unroll") for (int j = 0; j < 4; ++j)                             \
          acc1.q[j] += wh2 * cc1.q[j]; }                                        \
  }

#define LOADU(B0, B1, pp)                                                       \
  {                                                                             \
    int q = (pp) < dcap ? (pp) : dcap - 1;                                      \
    int s0 = __shfl(pre0, q, 64), s1 = __shfl(pre1, q, 64);                     \
    B0.v = *(const f16x8*)(xlr + (size_t)s0 * D2 + lane * 8);                   \
    B1.v = *(const f16x8*)(xlr + (size_t)s1 * D2 + lane * 8);                   \
  }

__global__ __launch_bounds__(256) void edge_agg10(const int* __restrict__ row_ptr,
                                                  const int* __restrict__ esrc,
                                                  const int* __restrict__ perm,
                                                  const f16* __restrict__ xlr,
                                                  const float* __restrict__ att,
                                                  const float* __restrict__ bias,
                                                  f16* __restrict__ out) {
    int wv = (blockIdx.x * 256 + threadIdx.x) >> 6;
    if (wv * 2 >= N_NODES) return;
    int n0 = perm[wv * 2], n1 = perm[wv * 2 + 1];
    int lane = threadIdx.x & 63;

    union U8 { f16x8 v; f16x2 q[4]; };
    U8 xr0, xr1;
    xr0.v = *(const f16x8*)(xlr + (size_t)n0 * D2 + DCH + lane * 8);
    xr1.v = *(const f16x8*)(xlr + (size_t)n1 * D2 + DCH + lane * 8);
    const float4* av = (const float4*)(att + lane * 8);
    float4 a0 = av[0], a1 = av[1];
    f16x2 at2[4] = { f16x2{(f16)a0.x, (f16)a0.y}, f16x2{(f16)a0.z, (f16)a0.w},
                     f16x2{(f16)a1.x, (f16)a1.y}, f16x2{(f16)a1.z, (f16)a1.w} };
    const f16x2 k02 = {(f16)0.2f, (f16)0.2f};

    int beg0 = row_ptr[n0], deg0 = row_ptr[n0 + 1] - beg0;
    int beg1 = row_ptr[n1], deg1 = row_ptr[n1 + 1] - beg1;
    int pre0 = (lane < deg0) ? esrc[beg0 + lane] : 0;
    int pre1 = (lane < deg1) ? esrc[beg1 + lane] : 0;

    U8 acc0, acc1;
    acc0.v = (f16x8)(f16)0.f;
    acc1.v = (f16x8)(f16)0.f;
    float m0 = -FLT_MAX, m1 = -FLT_MAX, d0 = 0.f, d1 = 0.f;

    int dmax = deg0 > deg1 ? deg0 : deg1;
    int dcap = dmax < 64 ? dmax : 64;

    // ring-4: buffers hold edges p..p+3; each PROC(p) is preceded by the load
    // of p+3 three PROCs earlier -> ~3x170cyc lookahead covers L3-hit latency.
    U8 cA0, cA1, cB0, cB1, cC0, cC1, cD0, cD1;
    LOADU(cA0, cA1, 0)
    LOADU(cB0, cB1, 1)
    LOADU(cC0, cC1, 2)
    for (int p = 0; p < dcap; p += 4) {      // unroll-4 rotation, static names
        LOADU(cD0, cD1, p + 3)
        PROC(cA0, cA1, p)
        if (p + 1 >= dcap) break;
        LOADU(cA0, cA1, p + 4)
        PROC(cB0, cB1, p + 1)
        if (p + 2 >= dcap) break;
        LOADU(cB0, cB1, p + 5)
        PROC(cC0, cC1, p + 2)
        if (p + 3 >= dcap) break;
        LOADU(cC0, cC1, p + 6)
        PROC(cD0, cD1, p + 3)
    }
    // rare tails: deg > 64 (LPT pairs similar degree)
    for (int p = 64; p < dmax; ++p) {
        int s0 = (p < deg0) ? esrc[beg0 + p] : 0;
        int s1 = (p < deg1) ? esrc[beg1 + p] : 0;
        U8 t0, t1;
        t0.v = *(const f16x8*)(xlr + (size_t)s0 * D2 + lane * 8);
        t1.v = *(const f16x8*)(xlr + (size_t)s1 * D2 + lane * 8);
        PROC(t0, t1, p)
    }

    const float4* bv = (const float4*)(bias + lane * 8);
    float4 b0 = bv[0], b1 = bv[1];
    float bf[8] = {b0.x, b0.y, b0.z, b0.w, b1.x, b1.y, b1.z, b1.w};
    float i0 = 1.f / d0, i1 = 1.f / d1;
    f16x8 o0, o1;
    #pragma unroll
    for (int j = 0; j < 8; ++j) {
        float v0 = (float)acc0.v[j] * i0 + bf[j];
        float v1 = (float)acc1.v[j] * i1 + bf[j];
        v0 = v0 > 0.f ? v0 : __expf(v0) - 1.f;   // ELU
        v1 = v1 > 0.f ? v1 : __expf(v1) - 1.f;
        o0[j] = (f16)v0;
        o1[j] = (f16)v1;
    }
    *(f16x8*)(out + (size_t)n0 * DCH + lane * 8) = o0;
    *(f16x8*)(out + (size_t)n1 * DCH + lane * 8) = o1;
}

// ---------------- launch ----------------
extern "C" void kernel_launch(void* const* d_in, const int* in_sizes, int n_in,
                              void* d_out, int out_size, void* d_ws, size_t ws_size,
                              hipStream_t stream) {
    const float* x     = (const float*)d_in[0];
    const int*   ei    = (const int*)d_in[1];
    const float* w1_l  = (const float*)d_in[2];
    const float* b1_l  = (const float*)d_in[3];
    const float* w1_r  = (const float*)d_in[4];
    const float* b1_r  = (const float*)d_in[5];
    const float* att1  = (const float*)d_in[6];
    const float* bias1 = (const float*)d_in[7];
    const float* w2_l  = (const float*)d_in[8];
    const float* b2_l  = (const float*)d_in[9];
    const float* w2_r  = (const float*)d_in[10];
    const float* b2_r  = (const float*)d_in[11];
    const float* att2  = (const float*)d_in[12];
    const float* bias2 = (const float*)d_in[13];
    const float* wcls  = (const float*)d_in[14];
    const float* bcls  = (const float*)d_in[15];
    float* out = (float*)d_out;

    char* ws = (char*)d_ws;
    f16* x_h = (f16*)ws;                                    // N*64
    f16* w1T = x_h + (size_t)N_NODES * INCHP;               // 1024*64
    f16* w2T = w1T + (size_t)D2 * INCHP;                    // 1024*512
    f16* wcT = w2T + (size_t)D2 * DCH;                      // 128*512
    f16* xlr = wcT + (size_t)OUTCHP * DCH;                  // N*1024
    f16* h   = xlr + (size_t)N_NODES * D2;                  // N*512
    int* row_ptr = (int*)(h + (size_t)N_NODES * DCH);       // N+1
    int* counts  = row_ptr + (N_NODES + 1);                 // N   } contiguous
    int* cursor  = counts + N_NODES;                        // N   } zero pair
    int* esrc    = cursor + N_NODES;                        // ET
    int* perm    = esrc + ET;                               // N
    int* bbase   = perm + N_NODES;                          // NB
    int* bcur    = bbase + NB;                              // NB

    // 1. fused prep
    prep_all<<<5317, 256, 0, stream>>>(x, x_h, w1_l, w1_r, w2_l, w2_r, wcls,
                                       w1T, w2T, wcT, counts, bcur);
    // 2-4. CSR + LPT degree-sorted permutation
    count_kernel<<<(ET + 255) / 256, 256, 0, stream>>>(ei, counts);
    scan_kernel<<<1, 1024, 0, stream>>>(counts, row_ptr, bbase);
    fill_perm_kernel<<<ETB + NPB, 256, 0, stream>>>(ei, row_ptr, counts, bbase,
                                                    cursor, bcur, esrc, perm);

    dim3 blk(256);
    dim3 gD(D2 / 128, (N_NODES + 127) / 128);               // 8 x 157
    dim3 gC(1, (N_NODES + 127) / 128);
    int eb = (N_NODES / 2 + 3) / 4;                         // 2 nodes/wave

    // layer 1 (fused l|r, K=64)
    gemm_f16<1, 1><<<gD, blk, 0, stream>>>(x_h, w1T, b1_l, b1_r, xlr, N_NODES, INCHP, D2, D2);
    edge_agg10<<<eb, blk, 0, stream>>>(row_ptr, esrc, perm, xlr, att1, bias1, h);
    // layer 2 (fused l|r, K=512)
    gemm_f16<1, 1><<<gD, blk, 0, stream>>>(h, w2T, b2_l, b2_r, xlr, N_NODES, DCH, D2, D2);
    edge_agg10<<<eb, blk, 0, stream>>>(row_ptr, esrc, perm, xlr, att2, bias2, h);
    // classifier (N padded 128, fp32 out)
    gemm_f16<0, 0><<<gC, blk, 0, stream>>>(h, wcT, bcls, bcls, out, N_NODES, DCH, OUTCH, OUTCH);
}

// Round 12
// 254.194 us; speedup vs baseline: 1.1625x; 1.0043x over previous
//
#include <hip/hip_runtime.h>
#include <hip/hip_bf16.h>
#include <float.h>
#include <math.h>

#define N_NODES 20000
#define N_EDGES 320000
#define ET      (N_EDGES + N_NODES)   // edges + self loops
#define ETB     ((ET + 255) / 256)     // fill blocks
#define NPB     ((N_NODES + 255) / 256)// perm blocks
#define DCH     512
#define D2      1024                   // fused l|r width
#define INCH    55
#define INCHP   64
#define OUTCH   49
#define OUTCHP  128
#define NB      130                    // degree buckets (clamped)

typedef _Float16 f16;
typedef _Float16 f16x2 __attribute__((ext_vector_type(2)));
typedef _Float16 f16x4 __attribute__((ext_vector_type(4)));
typedef _Float16 f16x8 __attribute__((ext_vector_type(8)));
typedef float    f32x4 __attribute__((ext_vector_type(4)));

#define GPTR(p) ((const __attribute__((address_space(1))) void*)(p))
#define LPTR(p) ((__attribute__((address_space(3))) void*)(p))

// ---------------- fused prep: zeroing + conv_x + 5 weight transposes ----------
__device__ __forceinline__ void transpose_tile(const float* __restrict__ w, f16* __restrict__ o,
                                               int K, int N, int Kp, int bx, int by, int t,
                                               f16 (*tile)[66]) {
    int k0 = by * 64, n0 = bx * 64;
    #pragma unroll
    for (int r = 0; r < 16; ++r) {
        int kl = (t >> 6) + r * 4, nl = t & 63;
        int gk = k0 + kl, gn = n0 + nl;
        tile[kl][nl] = (gk < K && gn < N) ? (f16)w[(size_t)gk * N + gn] : (f16)0.f;
    }
    __syncthreads();
    #pragma unroll
    for (int r = 0; r < 16; ++r) {
        int kl = t & 63, nl = (t >> 6) + r * 4;
        o[(size_t)(n0 + nl) * Kp + k0 + kl] = tile[kl][nl];
    }
}

__global__ __launch_bounds__(256) void prep_all(const float* __restrict__ x, f16* __restrict__ x_h,
                                                const float* __restrict__ w1l, const float* __restrict__ w1r,
                                                const float* __restrict__ w2l, const float* __restrict__ w2r,
                                                const float* __restrict__ wc,
                                                f16* __restrict__ w1T, f16* __restrict__ w2T,
                                                f16* __restrict__ wcT,
                                                int* __restrict__ zeroA,   // counts+cursor contiguous (40000)
                                                int* __restrict__ bcur) {
    __shared__ f16 tile[64][66];
    int b = blockIdx.x, t = threadIdx.x;
    if (b < 157) {
        int i = b * 256 + t;
        if (i < 40000) zeroA[i] = 0;
        else if (i < 40000 + NB) bcur[i - 40000] = 0;
        return;
    }
    b -= 157;
    if (b < 5000) {
        int i = b * 256 + t;
        int r = i >> 6, c = i & 63;
        x_h[i] = (c < INCH) ? (f16)x[r * INCH + c] : (f16)0.f;
        return;
    }
    b -= 5000;
    if (b < 8)  { transpose_tile(w1l, w1T, INCH, DCH, INCHP, b, 0, t, tile); return; }
    b -= 8;
    if (b < 8)  { transpose_tile(w1r, w1T + (size_t)DCH * INCHP, INCH, DCH, INCHP, b, 0, t, tile); return; }
    b -= 8;
    if (b < 64) { transpose_tile(w2l, w2T, DCH, DCH, DCH, b & 7, b >> 3, t, tile); return; }
    b -= 64;
    if (b < 64) { transpose_tile(w2r, w2T + (size_t)DCH * DCH, DCH, DCH, DCH, b & 7, b >> 3, t, tile); return; }
    b -= 64;
    transpose_tile(wc, wcT, DCH, OUTCH, DCH, b & 1, b >> 1, t, tile);
}

// ---------------- CSR build (by dst) ----------------
__global__ void count_kernel(const int* __restrict__ ei, int* __restrict__ counts) {
    int e = blockIdx.x * blockDim.x + threadIdx.x;
    if (e >= ET) return;
    int d = (e < N_EDGES) ? ei[N_EDGES + e] : (e - N_EDGES);
    atomicAdd(&counts[d], 1);
}

// node prefix-sum + degree-bucket histogram + DESCENDING bucket prefix (LPT)
__global__ void scan_kernel(const int* __restrict__ counts, int* __restrict__ row_ptr,
                            int* __restrict__ bbase) {
    __shared__ int sdata[1024];
    __shared__ int bh[NB];
    int t = threadIdx.x;
    if (t < NB) bh[t] = 0;
    __syncthreads();
    int per = (N_NODES + 1023) / 1024;
    int b = t * per, e = min(N_NODES, b + per);
    int sum = 0;
    for (int i = b; i < e; ++i) {
        int c = counts[i];
        sum += c;
        atomicAdd(&bh[min(c, NB - 1)], 1);
    }
    sdata[t] = sum;
    __syncthreads();
    for (int off = 1; off < 1024; off <<= 1) {
        int v = (t >= off) ? sdata[t - off] : 0;
        __syncthreads();
        sdata[t] += v;
        __syncthreads();
    }
    int run = (t == 0) ? 0 : sdata[t - 1];
    if (t == 0) row_ptr[0] = 0;
    for (int i = b; i < e; ++i) { run += counts[i]; row_ptr[i + 1] = run; }
    __syncthreads();
    if (t == 0) {
        int acc = 0;
        for (int j = NB - 1; j >= 0; --j) { bbase[j] = acc; acc += bh[j]; }  // LPT
    }
}

// fill CSR + degree-bucket scatter (hierarchical atomics). Intra-bucket order
// schedule-dependent; per-node outputs independent -> d_out deterministic.
__global__ __launch_bounds__(256) void fill_perm_kernel(const int* __restrict__ ei,
                                                        const int* __restrict__ row_ptr,
                                                        const int* __restrict__ counts,
                                                        const int* __restrict__ bbase,
                                                        int* __restrict__ cursor,
                                                        int* __restrict__ bcur,
                                                        int* __restrict__ esrc,
                                                        int* __restrict__ perm) {
    int blk = blockIdx.x;
    if (blk < ETB) {                        // CSR fill segment
        int e = blk * 256 + threadIdx.x;
        if (e >= ET) return;
        int s, d;
        if (e < N_EDGES) { s = ei[e]; d = ei[N_EDGES + e]; }
        else             { s = d = e - N_EDGES; }
        int pos = row_ptr[d] + atomicAdd(&cursor[d], 1);
        esrc[pos] = s;
        return;
    }
    blk -= ETB;
    __shared__ int hist[NB], basep[NB];
    int t = threadIdx.x;
    for (int i = t; i < NB; i += 256) hist[i] = 0;
    __syncthreads();
    int n = blk * 256 + t;
    bool valid = n < N_NODES;
    int bkt = 0, rl = 0;
    if (valid) {
        bkt = min(counts[n], NB - 1);
        rl = atomicAdd(&hist[bkt], 1);
    }
    __syncthreads();
    for (int i = t; i < NB; i += 256)
        if (hist[i] > 0) basep[i] = atomicAdd(&bcur[i], hist[i]);
    __syncthreads();
    if (valid) perm[bbase[bkt] + basep[bkt] + rl] = n;
}

// ---------------- fp16 MFMA GEMM: T3-recipe 2-phase double buffer --------------
// (guide §5.5 T3 "minimum 2-phase", m248-verified): per K-step, issue
// STAGE(next) BEFORE ds_read(cur)+MFMA, then ONE __syncthreads() (vmcnt(0)+
// barrier) -> load latency hides under 8 ds_read + 32 MFMA, and barrier count
// HALVES vs the old stage->sync->compute->sync loop. R8's failure kept
// per-phase drains (m218: drain-0 == no pipeline); this is the counted-overlap
// form. LDS 2x32KB = 64 KB -> 2 blocks/CU = 8 waves/CU (m248's verified TLP).
// T2 XOR swizzle + T1 XCD swizzle + operand-swap f16x4 epilogue retained.
template<int OUT_F16, int DUAL>
__global__ __launch_bounds__(256) void gemm_f16(const f16* __restrict__ A,
                                                const f16* __restrict__ BT,
                                                const float* __restrict__ bl,
                                                const float* __restrict__ br,
                                                void* __restrict__ Cout,
                                                int M, int Ka, int Nv, int ldc) {
    __shared__ __align__(16) f16 As[2][128][64];
    __shared__ __align__(16) f16 Bs[2][128][64];
    const int tid = threadIdx.x;
    const int w = tid >> 6, lane = tid & 63;
    int nbx = gridDim.x;
    int nwg = nbx * gridDim.y;
    int bid = blockIdx.y * nbx + blockIdx.x;
    if ((nwg & 7) == 0) bid = (bid & 7) * (nwg >> 3) + (bid >> 3);   // XCD swizzle (T1)
    const int m0 = (bid / nbx) * 128, n0 = (bid % nbx) * 128;
    const int wr = (w >> 1) * 64, wc = (w & 1) * 64;
    const int lrow = lane & 15, lk = lane >> 4;
    const int sw = lrow & 7;

    f32x4 acc[4][4] = {};

#define STAGE(BUF, KK0)                                                         \
    {                                                                           \
        _Pragma("unroll")                                                       \
        for (int i = 0; i < 4; ++i) {                                           \
            int idx = tid + 256 * i;                                            \
            int row = idx >> 3;                                                 \
            int cg  = (idx & 7) ^ (row & 7);                                    \
            int gm = m0 + row; gm = gm < M ? gm : M - 1;                        \
            const f16* gp = A + (size_t)gm * Ka + (KK0) + cg * 8;               \
            f16* lp = &As[BUF][0][0] + (size_t)(w * 64 + 256 * i) * 8;          \
            __builtin_amdgcn_global_load_lds(GPTR(gp), LPTR(lp), 16, 0, 0);     \
        }                                                                       \
        _Pragma("unroll")                                                       \
        for (int i = 0; i < 4; ++i) {                                           \
            int idx = tid + 256 * i;                                            \
            int row = idx >> 3;                                                 \
            int cg  = (idx & 7) ^ (row & 7);                                    \
            const f16* gp = BT + (size_t)(n0 + row) * Ka + (KK0) + cg * 8;      \
            f16* lp = &Bs[BUF][0][0] + (size_t)(w * 64 + 256 * i) * 8;          \
            __builtin_amdgcn_global_load_lds(GPTR(gp), LPTR(lp), 16, 0, 0);     \
        }                                                                       \
    }

    const int nt = Ka >> 6;                // K-steps of 64
    STAGE(0, 0)
    __syncthreads();                       // prologue: buf0 ready
    int cur = 0;
    for (int t = 0; t < nt; ++t) {
        if (t + 1 < nt) STAGE(cur ^ 1, (t + 1) * 64)   // issue next-tile loads
        __builtin_amdgcn_s_setprio(1);
        #pragma unroll
        for (int kk = 0; kk < 64; kk += 32) {
            f16x8 af[4], bf[4];
            #pragma unroll
            for (int m = 0; m < 4; ++m)
                af[m] = *(const f16x8*)&As[cur][wr + m * 16 + lrow][(((kk >> 3) + lk) ^ sw) * 8];
            #pragma unroll
            for (int n = 0; n < 4; ++n)
                bf[n] = *(const f16x8*)&Bs[cur][wc + n * 16 + lrow][(((kk >> 3) + lk) ^ sw) * 8];
            #pragma unroll
            for (int m = 0; m < 4; ++m)
                #pragma unroll
                for (int n = 0; n < 4; ++n)
                    acc[m][n] = __builtin_amdgcn_mfma_f32_16x16x32_f16(bf[n], af[m], acc[m][n], 0, 0, 0);
        }
        __builtin_amdgcn_s_setprio(0);
        __syncthreads();                   // drains my stage loads; next tile ready
        cur ^= 1;
    }
#undef STAGE

    // swapped C/D map: col(lane&15) -> m, row-group((lane>>4)*4+r) -> n
    const int om = lane & 15, on4 = (lane >> 4) * 4;
    #pragma unroll
    for (int nn = 0; nn < 4; ++nn) {
        int gn0 = n0 + wc + nn * 16 + on4;
        if (OUT_F16) {
            const float* bp = (DUAL && gn0 >= DCH) ? (br + gn0 - DCH) : (bl + gn0);
            float4 bv = *(const float4*)bp;
            float bfr[4] = {bv.x, bv.y, bv.z, bv.w};
            #pragma unroll
            for (int mm = 0; mm < 4; ++mm) {
                int gm = m0 + wr + mm * 16 + om;
                if (gm >= M) continue;
                f16x4 o;
                #pragma unroll
                for (int r = 0; r < 4; ++r) o[r] = (f16)(acc[mm][nn][r] + bfr[r]);
                *(f16x4*)((f16*)Cout + (size_t)gm * ldc + gn0) = o;
            }
        } else {
            #pragma unroll
            for (int mm = 0; mm < 4; ++mm) {
                int gm = m0 + wr + mm * 16 + om;
                if (gm >= M) continue;
                #pragma unroll
                for (int r = 0; r < 4; ++r) {
                    int gn = gn0 + r;
                    if (gn < Nv) ((float*)Cout)[(size_t)gm * ldc + gn] = acc[mm][nn][r] + bl[gn];
                }
            }
        }
    }
}

// ---------------- fused GATv2 edge phase v10 (UNCHANGED — at 3.4 TB/s L2-miss
// BW floor per R7-R11 plateau; pipeline depth no longer matters) ---------------
#define PROC(cc0, cc1, pp)                                                      \
  {                                                                             \
    float sc0 = 0.f, sc1 = 0.f;                                                 \
    _Pragma("unroll")                                                           \
    for (int j = 0; j < 4; ++j) {                                               \
        f16x2 u0 = cc0.q[j] + xr0.q[j];                                         \
        f16x2 u1 = cc1.q[j] + xr1.q[j];                                         \
        f16x2 l0 = __builtin_elementwise_max(u0, u0 * k02);                     \
        f16x2 l1 = __builtin_elementwise_max(u1, u1 * k02);                     \
        sc0 = __builtin_amdgcn_fdot2(l0, at2[j], sc0, false);                   \
        sc1 = __builtin_amdgcn_fdot2(l1, at2[j], sc1, false);                   \
    }                                                                           \
    _Pragma("unroll")                                                           \
    for (int o = 8; o >= 1; o >>= 1) {                                          \
        sc0 += __shfl_xor(sc0, o, 64);                                          \
        sc1 += __shfl_xor(sc1, o, 64);                                          \
    }                                                                           \
    if ((pp) >= deg0) sc0 = -INFINITY;                                          \
    if ((pp) >= deg1) sc1 = -INFINITY;                                          \
    if (__any(sc0 > m0 + 2.f)) {                                                \
        float mn = fmaxf(m0, sc0);                                              \
        f16 fh = (f16)__expf(m0 - mn);                                          \
        f16x2 fh2 = {fh, fh};                                                   \
        d0 *= (float)fh;                                                        \
        _Pragma("unroll") for (int j = 0; j < 4; ++j) acc0.q[j] *= fh2;         \
        m0 = mn;                                                                \
    }                                                                           \
    { f16 wh = (f16)__expf(sc0 - m0); d0 += (float)wh;                          \
      f16x2 wh2 = {wh, wh};                                                     \
      _Pragma("unroll") for (int j = 0; j < 4; ++j)                             \
          acc0.q[j] += wh2 * cc0.q[j]; }                                        \
    if (__any(sc1 > m1 + 2.f)) {                                                \
        float mn = fmaxf(m1, sc1);                                              \
        f16 fh = (f16)__expf(m1 - mn);                                          \
        f16x2 fh2 = {fh, fh};                                                   \
        d1 *= (float)fh;                                                        \
        _Pragma("unroll") for (int j = 0; j < 4; ++j) acc1.q[j] *= fh2;         \
        m1 = mn;                                                                \
    }                                                                           \
    { f16 wh = (f16)__expf(sc1 - m1); d1 += (float)wh;                          \
      f16x2 wh2 = {wh, wh};                                                     \
      _Pragma("unroll") for (int j = 0; j < 4; ++j)                             \
          acc1.q[j] += wh2 * cc1.q[j]; }                                        \
  }

#define LOADU(B0, B1, pp)                                                       \
  {                                                                             \
    int q = (pp) < dcap ? (pp) : dcap - 1;                                      \
    int s0 = __shfl(pre0, q, 64), s1 = __shfl(pre1, q, 64);                     \
    B0.v = *(const f16x8*)(xlr + (size_t)s0 * D2 + lane * 8);                   \
    B1.v = *(const f16x8*)(xlr + (size_t)s1 * D2 + lane * 8);                   \
  }

__global__ __launch_bounds__(256) void edge_agg10(const int* __restrict__ row_ptr,
                                                  const int* __restrict__ esrc,
                                                  const int* __restrict__ perm,
                                                  const f16* __restrict__ xlr,
                                                  const float* __restrict__ att,
                                                  const float* __restrict__ bias,
                                                  f16* __restrict__ out) {
    int wv = (blockIdx.x * 256 + threadIdx.x) >> 6;
    if (wv * 2 >= N_NODES) return;
    int n0 = perm[wv * 2], n1 = perm[wv * 2 + 1];
    int lane = threadIdx.x & 63;

    union U8 { f16x8 v; f16x2 q[4]; };
    U8 xr0, xr1;
    xr0.v = *(const f16x8*)(xlr + (size_t)n0 * D2 + DCH + lane * 8);
    xr1.v = *(const f16x8*)(xlr + (size_t)n1 * D2 + DCH + lane * 8);
    const float4* av = (const float4*)(att + lane * 8);
    float4 a0 = av[0], a1 = av[1];
    f16x2 at2[4] = { f16x2{(f16)a0.x, (f16)a0.y}, f16x2{(f16)a0.z, (f16)a0.w},
                     f16x2{(f16)a1.x, (f16)a1.y}, f16x2{(f16)a1.z, (f16)a1.w} };
    const f16x2 k02 = {(f16)0.2f, (f16)0.2f};

    int beg0 = row_ptr[n0], deg0 = row_ptr[n0 + 1] - beg0;
    int beg1 = row_ptr[n1], deg1 = row_ptr[n1 + 1] - beg1;
    int pre0 = (lane < deg0) ? esrc[beg0 + lane] : 0;
    int pre1 = (lane < deg1) ? esrc[beg1 + lane] : 0;

    U8 acc0, acc1;
    acc0.v = (f16x8)(f16)0.f;
    acc1.v = (f16x8)(f16)0.f;
    float m0 = -FLT_MAX, m1 = -FLT_MAX, d0 = 0.f, d1 = 0.f;

    int dmax = deg0 > deg1 ? deg0 : deg1;
    int dcap = dmax < 64 ? dmax : 64;

    U8 cA0, cA1, cB0, cB1, cC0, cC1, cD0, cD1;
    LOADU(cA0, cA1, 0)
    LOADU(cB0, cB1, 1)
    LOADU(cC0, cC1, 2)
    for (int p = 0; p < dcap; p += 4) {      // unroll-4 rotation, static names
        LOADU(cD0, cD1, p + 3)
        PROC(cA0, cA1, p)
        if (p + 1 >= dcap) break;
        LOADU(cA0, cA1, p + 4)
        PROC(cB0, cB1, p + 1)
        if (p + 2 >= dcap) break;
        LOADU(cB0, cB1, p + 5)
        PROC(cC0, cC1, p + 2)
        if (p + 3 >= dcap) break;
        LOADU(cC0, cC1, p + 6)
        PROC(cD0, cD1, p + 3)
    }
    // rare tails: deg > 64 (LPT pairs similar degree)
    for (int p = 64; p < dmax; ++p) {
        int s0 = (p < deg0) ? esrc[beg0 + p] : 0;
        int s1 = (p < deg1) ? esrc[beg1 + p] : 0;
        U8 t0, t1;
        t0.v = *(const f16x8*)(xlr + (size_t)s0 * D2 + lane * 8);
        t1.v = *(const f16x8*)(xlr + (size_t)s1 * D2 + lane * 8);
        PROC(t0, t1, p)
    }

    const float4* bv = (const float4*)(bias + lane * 8);
    float4 b0 = bv[0], b1 = bv[1];
    float bf[8] = {b0.x, b0.y, b0.z, b0.w, b1.x, b1.y, b1.z, b1.w};
    float i0 = 1.f / d0, i1 = 1.f / d1;
    f16x8 o0, o1;
    #pragma unroll
    for (int j = 0; j < 8; ++j) {
        float v0 = (float)acc0.v[j] * i0 + bf[j];
        float v1 = (float)acc1.v[j] * i1 + bf[j];
        v0 = v0 > 0.f ? v0 : __expf(v0) - 1.f;   // ELU
        v1 = v1 > 0.f ? v1 : __expf(v1) - 1.f;
        o0[j] = (f16)v0;
        o1[j] = (f16)v1;
    }
    *(f16x8*)(out + (size_t)n0 * DCH + lane * 8) = o0;
    *(f16x8*)(out + (size_t)n1 * DCH + lane * 8) = o1;
}

// ---------------- launch ----------------
extern "C" void kernel_launch(void* const* d_in, const int* in_sizes, int n_in,
                              void* d_out, int out_size, void* d_ws, size_t ws_size,
                              hipStream_t stream) {
    const float* x     = (const float*)d_in[0];
    const int*   ei    = (const int*)d_in[1];
    const float* w1_l  = (const float*)d_in[2];
    const float* b1_l  = (const float*)d_in[3];
    const float* w1_r  = (const float*)d_in[4];
    const float* b1_r  = (const float*)d_in[5];
    const float* att1  = (const float*)d_in[6];
    const float* bias1 = (const float*)d_in[7];
    const float* w2_l  = (const float*)d_in[8];
    const float* b2_l  = (const float*)d_in[9];
    const float* w2_r  = (const float*)d_in[10];
    const float* b2_r  = (const float*)d_in[11];
    const float* att2  = (const float*)d_in[12];
    const float* bias2 = (const float*)d_in[13];
    const float* wcls  = (const float*)d_in[14];
    const float* bcls  = (const float*)d_in[15];
    float* out = (float*)d_out;

    char* ws = (char*)d_ws;
    f16* x_h = (f16*)ws;                                    // N*64
    f16* w1T = x_h + (size_t)N_NODES * INCHP;               // 1024*64
    f16* w2T = w1T + (size_t)D2 * INCHP;                    // 1024*512
    f16* wcT = w2T + (size_t)D2 * DCH;                      // 128*512
    f16* xlr = wcT + (size_t)OUTCHP * DCH;                  // N*1024
    f16* h   = xlr + (size_t)N_NODES * D2;                  // N*512
    int* row_ptr = (int*)(h + (size_t)N_NODES * DCH);       // N+1
    int* counts  = row_ptr + (N_NODES + 1);                 // N   } contiguous
    int* cursor  = counts + N_NODES;                        // N   } zero pair
    int* esrc    = cursor + N_NODES;                        // ET
    int* perm    = esrc + ET;                               // N
    int* bbase   = perm + N_NODES;                          // NB
    int* bcur    = bbase + NB;                              // NB

    // 1. fused prep
    prep_all<<<5317, 256, 0, stream>>>(x, x_h, w1_l, w1_r, w2_l, w2_r, wcls,
                                       w1T, w2T, wcT, counts, bcur);
    // 2-4. CSR + LPT degree-sorted permutation
    count_kernel<<<(ET + 255) / 256, 256, 0, stream>>>(ei, counts);
    scan_kernel<<<1, 1024, 0, stream>>>(counts, row_ptr, bbase);
    fill_perm_kernel<<<ETB + NPB, 256, 0, stream>>>(ei, row_ptr, counts, bbase,
                                                    cursor, bcur, esrc, perm);

    dim3 blk(256);
    dim3 gD(D2 / 128, (N_NODES + 127) / 128);               // 8 x 157
    dim3 gC(1, (N_NODES + 127) / 128);
    int eb = (N_NODES / 2 + 3) / 4;                         // 2 nodes/wave

    // layer 1 (fused l|r, K=64)
    gemm_f16<1, 1><<<gD, blk, 0, stream>>>(x_h, w1T, b1_l, b1_r, xlr, N_NODES, INCHP, D2, D2);
    edge_agg10<<<eb, blk, 0, stream>>>(row_ptr, esrc, perm, xlr, att1, bias1, h);
    // layer 2 (fused l|r, K=512)
    gemm_f16<1, 1><<<gD, blk, 0, stream>>>(h, w2T, b2_l, b2_r, xlr, N_NODES, DCH, D2, D2);
    edge_agg10<<<eb, blk, 0, stream>>>(row_ptr, esrc, perm, xlr, att2, bias2, h);
    // classifier (N padded 128, fp32 out)
    gemm_f16<0, 0><<<gC, blk, 0, stream>>>(h, wcT, bcls, bcls, out, N_NODES, DCH, OUTCH, OUTCH);
}